// Round 7
// baseline (179.419 us; speedup 1.0000x reference)
//
#include <hip/hip_runtime.h>
#include <math.h>

#define BB 32
#define SS 2048
#define EE 128
#define NH 8
#define HDIM 16
#define CACHE_LEN 256
#define SINKS 4
#define WINDOW 128
#define KSEL (SINKS + WINDOW)   // 132
#define ROWS (BB * SS)          // 65536

typedef int v4i __attribute__((ext_vector_type(4)));
typedef _Float16 f16x4 __attribute__((ext_vector_type(4)));
typedef _Float16 f16x8 __attribute__((ext_vector_type(8)));
typedef __fp16 fp16v2 __attribute__((ext_vector_type(2)));
typedef float f32x4 __attribute__((ext_vector_type(4)));

// workspace layout (bytes)
#define WS_WS   16                        // float[4] w_scales (q,k,v,o)
#define WS_W(i) (256 + (i) * 16384)       // ternary int8, row-major [o][e]
#define WS_QBUF (256 + 4 * 16384)         // q rows, head-major: [b][h][s][16] f16, 0.25 folded
#define WS_PMAXX (WS_QBUF + 16777216)     // float[2048] per-block |x| maxes
#define WS_PMAXO (WS_PMAXX + 8192)        // float[1024] per-block |attn_out| maxes
#define WS_ABUF  (WS_PMAXO + 8192)        // attn-out f16 [b][s][128] (16.8 MB)

// d_out layout: [0, ROWS*128) final output; new_k at ROWS*128, new_v after
#define NKV_N (BB * NH * WINDOW * HDIM)   // 524288

// ---- fused weight prep (blocks 0..3) + max|x| partials (blocks 4..2051) --
__global__ __launch_bounds__(256) void prep_and_max(const float* __restrict__ qw,
                                                    const float* __restrict__ kw,
                                                    const float* __restrict__ vw,
                                                    const float* __restrict__ ow,
                                                    const float* __restrict__ x,
                                                    char* __restrict__ ws) {
    const int tid = threadIdx.x;
    if (blockIdx.x < 4) {
        const float* W[4] = {qw, kw, vw, ow};
        const int m = blockIdx.x;
        const float4* w4 = (const float4*)W[m];
        __shared__ double red[256];
        double sA = 0.0, sB = 0.0;
        for (int j = tid; j < 4096; j += 256) {
            const float4 v = w4[j];
            sA += fabs((double)v.x) + fabs((double)v.z);
            sB += fabs((double)v.y) + fabs((double)v.w);
        }
        red[tid] = sA + sB;
        __syncthreads();
        for (int st = 128; st > 0; st >>= 1) {
            if (tid < st) red[tid] += red[tid + st];
            __syncthreads();
        }
        const double wscale = red[0] / 16384.0;
        const double thr = 0.5 * wscale;
        if (tid == 0) ((float*)(ws + WS_WS))[m] = (float)wscale;
        int* tw = (int*)(ws + WS_W(m));
        for (int j = tid; j < 4096; j += 256) {
            const float4 v = w4[j];
            const int b0 = (fabs((double)v.x) > thr) ? (v.x > 0.f ? 1 : -1) : 0;
            const int b1 = (fabs((double)v.y) > thr) ? (v.y > 0.f ? 1 : -1) : 0;
            const int b2 = (fabs((double)v.z) > thr) ? (v.z > 0.f ? 1 : -1) : 0;
            const int b3 = (fabs((double)v.w) > thr) ? (v.w > 0.f ? 1 : -1) : 0;
            tw[j] = (b0 & 0xff) | ((b1 & 0xff) << 8) | ((b2 & 0xff) << 16) | (b3 << 24);
        }
    } else {
        // 2048 blocks x 1024 float4s, fully unrolled independent loads
        const int idx = blockIdx.x - 4;
        const float4* x4 = (const float4*)x + (size_t)idx * 1024;
        float m0[4];
#pragma unroll
        for (int k = 0; k < 4; ++k) {
            const float4 v = x4[k * 256 + tid];
            m0[k] = fmaxf(fmaxf(fabsf(v.x), fabsf(v.y)), fmaxf(fabsf(v.z), fabsf(v.w)));
        }
        float mx = fmaxf(fmaxf(m0[0], m0[1]), fmaxf(m0[2], m0[3]));
#pragma unroll
        for (int off = 32; off; off >>= 1) mx = fmaxf(mx, __shfl_xor(mx, off));
        __shared__ float wred[4];
        if ((tid & 63) == 0) wred[tid >> 6] = mx;
        __syncthreads();
        if (tid == 0)
            ((float*)(ws + WS_PMAXX))[idx] =
                fmaxf(fmaxf(wred[0], wred[1]), fmaxf(wred[2], wred[3]));
    }
}

// ---- int8 MFMA QKV projection -------------------------------------------
// x loads are issued BEFORE the max-reduction prologue so HBM latency hides
// under it. Prologue folds the 2048-partial max|x| reduction (L2-hit).
// blocks 0..1023: Q (all rows) -> QBUF head-major f16 (0.25 scale folded)
// blocks 1024..1151: K,V (window rows only) -> new_k/new_v region of d_out
__global__ __launch_bounds__(256) void qkv_proj_mfma(const float* __restrict__ x,
                                                     const float* __restrict__ qb,
                                                     const float* __restrict__ kb,
                                                     const float* __restrict__ vb,
                                                     char* __restrict__ ws,
                                                     float* __restrict__ out) {
    const int bx = blockIdx.x;
    const int tid = threadIdx.x;
    int proj, in_row0, b_blk, s0;   // s0: seq offset (Q) or window offset (K/V)
    if (bx < 1024) {
        proj = 0; in_row0 = bx * 64; b_blk = bx >> 5; s0 = (bx * 64) & 2047;
    } else {
        int widx = bx - 1024;
        proj = 1 + (widx >> 6);
        widx &= 63;
        b_blk = widx >> 1;
        s0 = (widx & 1) * 64;
        in_row0 = b_blk * 2048 + (SS - WINDOW) + s0;
    }
    const float* bias = (proj == 0) ? qb : (proj == 1) ? kb : vb;
    const signed char* tw = (const signed char*)(ws + WS_W(proj));
    float* dst = (proj == 1) ? (out + (size_t)ROWS * EE)
                             : (out + (size_t)ROWS * EE + NKV_N);   // K or V (unused for Q)
    _Float16* dstq = (_Float16*)(ws + WS_QBUF);

    const int lane = tid & 63;
    const int wv = tid >> 6;
    const int ml = lane & 15;
    const int quad = lane >> 4;

    // ---- issue all x loads first (latency hidden under prologue) ----
    const float4* x4 = (const float4*)(x + (size_t)in_row0 * 128);
    float4 xa[8];
#pragma unroll
    for (int it = 0; it < 8; ++it) xa[it] = x4[tid + it * 256];

    // ---- prologue: reduce 2048 partial |x| maxes -> maxx ----
    __shared__ float xred[4];
    {
        const float4* pm = (const float4*)(ws + WS_PMAXX);
        float mo = 0.f;
#pragma unroll
        for (int k = 0; k < 2; ++k) {
            const float4 v = pm[k * 256 + tid];
            mo = fmaxf(mo, fmaxf(fmaxf(v.x, v.y), fmaxf(v.z, v.w)));
        }
#pragma unroll
        for (int off = 32; off; off >>= 1) mo = fmaxf(mo, __shfl_xor(mo, off));
        if ((tid & 63) == 0) xred[tid >> 6] = mo;
    }

    v4i bfrag[8][2];
#pragma unroll
    for (int c = 0; c < 8; ++c)
#pragma unroll
        for (int s = 0; s < 2; ++s)
            bfrag[c][s] = *(const v4i*)(tw + (c * 16 + ml) * 128 + s * 64 + quad * 16);

    __syncthreads();
    const float maxx = fmaxf(fmaxf(xred[0], xred[1]), fmaxf(xred[2], xred[3]));

    __shared__ __align__(16) signed char lds_a[64 * 144];
    const float iscale = maxx / 127.0f;
    const float inv = 1.0f / iscale;
#pragma unroll
    for (int it = 0; it < 8; ++it) {
        const int i = tid + it * 256;
        const int row = i >> 5, c4 = i & 31;
        const float4 v = xa[it];
        // |x| <= maxx guarantees |x|*inv <= 127: no clamp needed
        const int i0 = (int)rintf(v.x * inv);
        const int i1 = (int)rintf(v.y * inv);
        const int i2 = (int)rintf(v.z * inv);
        const int i3 = (int)rintf(v.w * inv);
        const int packed = (i0 & 0xff) | ((i1 & 0xff) << 8) | ((i2 & 0xff) << 16) | (i3 << 24);
        *(int*)(lds_a + row * 144 + c4 * 4) = packed;
    }
    __syncthreads();

    const v4i afrag0 = *(const v4i*)(lds_a + (wv * 16 + ml) * 144 + quad * 16);
    const v4i afrag1 = *(const v4i*)(lds_a + (wv * 16 + ml) * 144 + 64 + quad * 16);

    const float wsc = ((const float*)(ws + WS_WS))[proj];
    const float scale = wsc * iscale;
    const int srow = s0 + wv * 16 + ml;

#pragma unroll
    for (int c = 0; c < 8; ++c) {
        v4i acc = {0, 0, 0, 0};
        // swapped operands: D = W · X^T ; lane(ml,quad) reg r = out[row=ml][col=c*16+quad*4+r]
        acc = __builtin_amdgcn_mfma_i32_16x16x64_i8(bfrag[c][0], afrag0, acc, 0, 0, 0);
        acc = __builtin_amdgcn_mfma_i32_16x16x64_i8(bfrag[c][1], afrag1, acc, 0, 0, 0);
        const float4 b4 = ((const float4*)bias)[c * 4 + quad];
        if (proj == 0) {
            f16x4 st;
            st[0] = (_Float16)(((float)acc[0] * scale + b4.x) * 0.25f);
            st[1] = (_Float16)(((float)acc[1] * scale + b4.y) * 0.25f);
            st[2] = (_Float16)(((float)acc[2] * scale + b4.z) * 0.25f);
            st[3] = (_Float16)(((float)acc[3] * scale + b4.w) * 0.25f);
            *(f16x4*)(dstq + ((size_t)(b_blk * NH + c) * SS + srow) * 16 + quad * 4) = st;
        } else {
            float4 st;
            st.x = (float)acc[0] * scale + b4.x;
            st.y = (float)acc[1] * scale + b4.y;
            st.z = (float)acc[2] * scale + b4.z;
            st.w = (float)acc[3] * scale + b4.w;
            *(float4*)(dst + ((size_t)(b_blk * NH + c) * WINDOW + srow) * 16 + quad * 4) = st;
        }
    }
}

// ---- attention: f16 MFMA, latency-optimized -----------------------------
// 4 blocks per (b,h) x 512 queries: K/V staged HALF as often as the old
// 8-block split. K staged f16 [j][d], V staged f16 TRANSPOSED [d][j];
// Q fragments (8) prefetched; tree reductions; dual PV accumulators.
// Output written f16 to WS_ABUF.
__global__ __launch_bounds__(256, 4) void attention(const float* __restrict__ ck,
                                                    const float* __restrict__ cv,
                                                    char* __restrict__ ws,
                                                    float* __restrict__ out) {
    const int qs = blockIdx.x, h = blockIdx.y, b = blockIdx.z;
    __shared__ __align__(16) _Float16 ksh[144 * 16];   // [j][d]
    __shared__ __align__(16) _Float16 vshT[16 * 144];  // [d][j]
    __shared__ float red[256];
    const int tid = threadIdx.x;
    const float* nkbuf = out + (size_t)ROWS * EE;
    const float* nvbuf = nkbuf + NKV_N;
    _Float16* abuf = (_Float16*)(ws + WS_ABUF);

    // --- staging: window rows 4..131 vectorized, sinks 0..3, zero tail ---
    {
        const float4* kw4 = (const float4*)(nkbuf + (size_t)(b * NH + h) * WINDOW * 16);
        const float4* vw4 = (const float4*)(nvbuf + (size_t)(b * NH + h) * WINDOW * 16);
#pragma unroll
        for (int it = 0; it < 2; ++it) {
            const int i = tid + it * 256;          // 0..511 float4s
            const float4 kv = kw4[i];
            const float4 vv = vw4[i];
            const int j = 4 + (i >> 2);
            const int d0 = (i & 3) * 4;
            f16x4 kh;
            kh[0] = (_Float16)kv.x; kh[1] = (_Float16)kv.y;
            kh[2] = (_Float16)kv.z; kh[3] = (_Float16)kv.w;
            *(f16x4*)(ksh + j * 16 + d0) = kh;
            vshT[(d0 + 0) * 144 + j] = (_Float16)vv.x;
            vshT[(d0 + 1) * 144 + j] = (_Float16)vv.y;
            vshT[(d0 + 2) * 144 + j] = (_Float16)vv.z;
            vshT[(d0 + 3) * 144 + j] = (_Float16)vv.w;
        }
        if (tid < 64) {                            // sinks j=0..3
            const int j = tid >> 4, d = tid & 15;
            const float kv = ck[((size_t)(b * NH + h) * CACHE_LEN + j) * 16 + d];
            const float vv = cv[((size_t)(b * NH + h) * CACHE_LEN + j) * 16 + d];
            ksh[j * 16 + d] = (_Float16)kv;
            vshT[d * 144 + j] = (_Float16)vv;
        } else {                                   // zero tail j=132..143 (192 elems)
            const int e = tid - 64;
            const int j = 132 + (e >> 4), d = e & 15;
            ksh[j * 16 + d] = (_Float16)0.f;
            vshT[d * 144 + j] = (_Float16)0.f;
        }
    }
    __syncthreads();

    const int lane = tid & 63;
    const int wv = tid >> 6;
    const int ml = lane & 15;
    const int quad = lane >> 4;

    // K A-fragments: lane holds K[c*16+ml][quad*4 .. +3]
    // V^T A-fragments: lane holds V[c*16+quad*4+i][ml] = vshT[ml][c*16+quad*4+i]
    f16x4 kf[9], vf[9];
#pragma unroll
    for (int c = 0; c < 9; ++c) {
        kf[c] = *(const f16x4*)(ksh + (c * 16 + ml) * 16 + quad * 4);
        vf[c] = *(const f16x4*)(vshT + ml * 144 + c * 16 + quad * 4);
    }

    // prefetch all 8 Q fragments (batch the HBM latency)
    const _Float16* qbuf = (const _Float16*)(ws + WS_QBUF) + (size_t)(b * NH + h) * SS * 16;
    f16x4 qf[8];
#pragma unroll
    for (int t = 0; t < 8; ++t) {
        const int q0 = qs * 512 + (t * 4 + wv) * 16;
        qf[t] = *(const f16x4*)(qbuf + (size_t)(q0 + ml) * 16 + quad * 4);
    }

    float tm = 0.f;

#pragma unroll 1
    for (int t = 0; t < 8; ++t) {
        const int q0 = qs * 512 + (t * 4 + wv) * 16;

        // S^T[j][q]: lane (ml,quad) reg r holds score(j = c*16+quad*4+r, q = q0+ml)
        f32x4 s[9];
#pragma unroll
        for (int c = 0; c < 9; ++c) {
            f32x4 z = {0.f, 0.f, 0.f, 0.f};
            s[c] = __builtin_amdgcn_mfma_f32_16x16x16f16(kf[c], qf[t], z, 0, 0, 0);
        }
        // padded tail keys j=132..143 (chunk 8, quad>=1) are invalid
        if (quad >= 1) {
#pragma unroll
            for (int r = 0; r < 4; ++r) s[8][r] = -1e30f;
        }
        // causal mask: query q attends keys j <= min(q, 131); only q<=130 need it
        if (q0 <= 130) {
            const int jm = min(q0 + ml, KSEL - 1);
#pragma unroll
            for (int c = 0; c < 9; ++c)
#pragma unroll
                for (int r = 0; r < 4; ++r)
                    if (c * 16 + quad * 4 + r > jm) s[c][r] = -1e30f;
        }

        // ---- max: pairwise tree (depth ~6) + 2 shfl ----
        float mc[9];
#pragma unroll
        for (int c = 0; c < 9; ++c)
            mc[c] = fmaxf(fmaxf(s[c][0], s[c][1]), fmaxf(s[c][2], s[c][3]));
        const float t01 = fmaxf(mc[0], mc[1]), t23 = fmaxf(mc[2], mc[3]);
        const float t45 = fmaxf(mc[4], mc[5]), t67 = fmaxf(mc[6], mc[7]);
        float mx = fmaxf(fmaxf(fmaxf(t01, t23), fmaxf(t45, t67)), mc[8]);
        mx = fmaxf(mx, __shfl_xor(mx, 16));
        mx = fmaxf(mx, __shfl_xor(mx, 32));

        // ---- exp + sum: 4 parallel partial-sum chains ----
        f32x4 ls = {0.f, 0.f, 0.f, 0.f};
#pragma unroll
        for (int c = 0; c < 9; ++c) {
#pragma unroll
            for (int r = 0; r < 4; ++r) {
                const float p = __expf(s[c][r] - mx);
                s[c][r] = p;
                ls[r] += p;
            }
        }
        float lsum = (ls[0] + ls[1]) + (ls[2] + ls[3]);
        lsum += __shfl_xor(lsum, 16);
        lsum += __shfl_xor(lsum, 32);

        // ---- PV: O^T = V^T · P^T, dual accumulators (halved dep chain) ----
        f32x4 oA = {0.f, 0.f, 0.f, 0.f}, oB = {0.f, 0.f, 0.f, 0.f};
#pragma unroll
        for (int c = 0; c < 9; ++c) {
            union { fp16v2 h2[2]; f16x4 h4; } u;
            u.h2[0] = __builtin_amdgcn_cvt_pkrtz(s[c][0], s[c][1]);
            u.h2[1] = __builtin_amdgcn_cvt_pkrtz(s[c][2], s[c][3]);
            if (c & 1) oB = __builtin_amdgcn_mfma_f32_16x16x16f16(vf[c], u.h4, oB, 0, 0, 0);
            else       oA = __builtin_amdgcn_mfma_f32_16x16x16f16(vf[c], u.h4, oA, 0, 0, 0);
        }

        const float inv = 1.0f / lsum;
        float4 ov;
        ov.x = (oA[0] + oB[0]) * inv;
        ov.y = (oA[1] + oB[1]) * inv;
        ov.z = (oA[2] + oB[2]) * inv;
        ov.w = (oA[3] + oB[3]) * inv;
        tm = fmaxf(tm, fmaxf(fmaxf(fabsf(ov.x), fabsf(ov.y)), fmaxf(fabsf(ov.z), fabsf(ov.w))));
        // lane writes f16 O[q0+ml][quad*4 .. +3] of head h into ABUF
        f16x4 oh;
        oh[0] = (_Float16)ov.x; oh[1] = (_Float16)ov.y;
        oh[2] = (_Float16)ov.z; oh[3] = (_Float16)ov.w;
        *(f16x4*)(abuf + ((size_t)(b * SS + q0 + ml)) * 128 + h * 16 + quad * 4) = oh;
    }

    red[tid] = tm;
    __syncthreads();
    for (int st = 128; st > 0; st >>= 1) {
        if (tid < st) red[tid] = fmaxf(red[tid], red[tid + st]);
        __syncthreads();
    }
    if (tid == 0) {
        const int id = qs + 4 * h + 32 * b;      // 0..1023
        ((float*)(ws + WS_PMAXO))[id] = red[0];
    }
}

// ---- O projection, int8 MFMA: reads f16 ABUF, writes final f32 d_out ----
// ABUF loads issued BEFORE the 1024-partial maxo reduction (latency hidden).
__global__ __launch_bounds__(256) void o_proj_mfma(const float* __restrict__ ob,
                                                   char* __restrict__ ws,
                                                   float* __restrict__ out) {
    const int bx = blockIdx.x;
    const int tid = threadIdx.x;
    const int in_row0 = bx * 64;
    const signed char* tw = (const signed char*)(ws + WS_W(3));

    const int lane = tid & 63;
    const int wv = tid >> 6;
    const int ml = lane & 15;
    const int quad = lane >> 4;

    // ---- issue all ABUF loads first ----
    const _Float16* abuf = (const _Float16*)(ws + WS_ABUF);
    f16x8 av[4];
#pragma unroll
    for (int it = 0; it < 4; ++it) {
        const int i = tid + it * 256;              // 0..1023 f16x8 chunks
        const int row = i >> 4, c8 = i & 15;
        av[it] = *(const f16x8*)(abuf + (size_t)(in_row0 + row) * 128 + c8 * 8);
    }

    // ---- reduce 1024 partial maxes -> maxo ----
    __shared__ float ored[4];
    {
        const float4 v = ((const float4*)(ws + WS_PMAXO))[tid];   // 256 x 4 = 1024
        float mo = fmaxf(fmaxf(v.x, v.y), fmaxf(v.z, v.w));
#pragma unroll
        for (int off = 32; off; off >>= 1) mo = fmaxf(mo, __shfl_xor(mo, off));
        if ((tid & 63) == 0) ored[tid >> 6] = mo;
    }

    v4i bfrag[8][2];
#pragma unroll
    for (int c = 0; c < 8; ++c)
#pragma unroll
        for (int s = 0; s < 2; ++s)
            bfrag[c][s] = *(const v4i*)(tw + (c * 16 + ml) * 128 + s * 64 + quad * 16);

    __syncthreads();
    const float maxo = fmaxf(fmaxf(ored[0], ored[1]), fmaxf(ored[2], ored[3]));

    __shared__ __align__(16) signed char lds_a[64 * 144];
    const float iscale = maxo / 127.0f;
    const float inv = 1.0f / iscale;
#pragma unroll
    for (int it = 0; it < 4; ++it) {
        const int i = tid + it * 256;
        const int row = i >> 4, c8 = i & 15;
        const f16x8 v = av[it];
        // |attn_out| <= maxo (f16 round-up <= 0.05% -> still rints to <=127)
        const int i0 = (int)rintf((float)v[0] * inv);
        const int i1 = (int)rintf((float)v[1] * inv);
        const int i2 = (int)rintf((float)v[2] * inv);
        const int i3 = (int)rintf((float)v[3] * inv);
        const int i4 = (int)rintf((float)v[4] * inv);
        const int i5 = (int)rintf((float)v[5] * inv);
        const int i6 = (int)rintf((float)v[6] * inv);
        const int i7 = (int)rintf((float)v[7] * inv);
        const int p0 = (i0 & 0xff) | ((i1 & 0xff) << 8) | ((i2 & 0xff) << 16) | (i3 << 24);
        const int p1 = (i4 & 0xff) | ((i5 & 0xff) << 8) | ((i6 & 0xff) << 16) | (i7 << 24);
        *(int*)(lds_a + row * 144 + c8 * 8) = p0;
        *(int*)(lds_a + row * 144 + c8 * 8 + 4) = p1;
    }
    __syncthreads();

    const v4i afrag0 = *(const v4i*)(lds_a + (wv * 16 + ml) * 144 + quad * 16);
    const v4i afrag1 = *(const v4i*)(lds_a + (wv * 16 + ml) * 144 + 64 + quad * 16);

    const float wsc = ((const float*)(ws + WS_WS))[3];
    const float scale = wsc * iscale;
    const int orow = in_row0 + wv * 16 + ml;

#pragma unroll
    for (int c = 0; c < 8; ++c) {
        v4i acc = {0, 0, 0, 0};
        // swapped operands: lane(ml,quad) reg r = out[row=ml][col=c*16+quad*4+r]
        acc = __builtin_amdgcn_mfma_i32_16x16x64_i8(bfrag[c][0], afrag0, acc, 0, 0, 0);
        acc = __builtin_amdgcn_mfma_i32_16x16x64_i8(bfrag[c][1], afrag1, acc, 0, 0, 0);
        const float4 b4 = ((const float4*)ob)[c * 4 + quad];
        float4 st;
        st.x = (float)acc[0] * scale + b4.x;
        st.y = (float)acc[1] * scale + b4.y;
        st.z = (float)acc[2] * scale + b4.z;
        st.w = (float)acc[3] * scale + b4.w;
        *(float4*)(out + (size_t)orow * 128 + c * 16 + quad * 4) = st;
    }
}

extern "C" void kernel_launch(void* const* d_in, const int* in_sizes, int n_in,
                              void* d_out, int out_size, void* d_ws, size_t ws_size,
                              hipStream_t stream) {
    const float* x  = (const float*)d_in[0];
    const float* ck = (const float*)d_in[1];
    const float* cv = (const float*)d_in[2];
    const float* qw = (const float*)d_in[3];
    const float* qb = (const float*)d_in[4];
    const float* kw = (const float*)d_in[5];
    const float* kb = (const float*)d_in[6];
    const float* vw = (const float*)d_in[7];
    const float* vb = (const float*)d_in[8];
    const float* ow = (const float*)d_in[9];
    const float* ob = (const float*)d_in[10];
    char* ws = (char*)d_ws;
    float* out = (float*)d_out;

    prep_and_max<<<4 + 2048, 256, 0, stream>>>(qw, kw, vw, ow, x, ws);
    qkv_proj_mfma<<<1024 + 128, 256, 0, stream>>>(x, qb, kb, vb, ws, out);
    attention<<<dim3(4, NH, BB), 256, 0, stream>>>(ck, cv, ws, out);
    o_proj_mfma<<<1024, 256, 0, stream>>>(ob, ws, out);
}

// Round 8
// 169.423 us; speedup vs baseline: 1.0590x; 1.0590x over previous
//
#include <hip/hip_runtime.h>
#include <math.h>

#define BB 32
#define SS 2048
#define EE 128
#define NH 8
#define HDIM 16
#define CACHE_LEN 256
#define SINKS 4
#define WINDOW 128
#define KSEL (SINKS + WINDOW)   // 132
#define ROWS (BB * SS)          // 65536

typedef int v4i __attribute__((ext_vector_type(4)));
typedef _Float16 f16x4 __attribute__((ext_vector_type(4)));
typedef _Float16 f16x8 __attribute__((ext_vector_type(8)));
typedef __fp16 fp16v2 __attribute__((ext_vector_type(2)));
typedef float f32x4 __attribute__((ext_vector_type(4)));

// workspace layout (bytes)
#define WS_WS   16                        // float[4] w_scales (q,k,v,o)
#define WS_W(i) (256 + (i) * 16384)       // ternary int8, row-major [o][e]
#define WS_QBUF (256 + 4 * 16384)         // q rows, head-major: [b][h][s][16] f16, 0.25 folded
#define WS_PMAXX (WS_QBUF + 16777216)     // float[2048] per-block |x| maxes
#define WS_PMAXO (WS_PMAXX + 8192)        // float[2048] per-block |attn_out| maxes
#define WS_ABUF  (WS_PMAXO + 8192)        // attn-out f16 [b][s][128] (16.8 MB)

// d_out layout: [0, ROWS*128) final output; new_k at ROWS*128, new_v after
#define NKV_N (BB * NH * WINDOW * HDIM)   // 524288

// ---- fused weight prep (blocks 0..3) + max|x| partials (blocks 4..2051) --
__global__ __launch_bounds__(256) void prep_and_max(const float* __restrict__ qw,
                                                    const float* __restrict__ kw,
                                                    const float* __restrict__ vw,
                                                    const float* __restrict__ ow,
                                                    const float* __restrict__ x,
                                                    char* __restrict__ ws) {
    const int tid = threadIdx.x;
    if (blockIdx.x < 4) {
        const float* W[4] = {qw, kw, vw, ow};
        const int m = blockIdx.x;
        const float4* w4 = (const float4*)W[m];
        __shared__ double red[256];
        double sA = 0.0, sB = 0.0;
        for (int j = tid; j < 4096; j += 256) {
            const float4 v = w4[j];
            sA += fabs((double)v.x) + fabs((double)v.z);
            sB += fabs((double)v.y) + fabs((double)v.w);
        }
        red[tid] = sA + sB;
        __syncthreads();
        for (int st = 128; st > 0; st >>= 1) {
            if (tid < st) red[tid] += red[tid + st];
            __syncthreads();
        }
        const double wscale = red[0] / 16384.0;
        const double thr = 0.5 * wscale;
        if (tid == 0) ((float*)(ws + WS_WS))[m] = (float)wscale;
        int* tw = (int*)(ws + WS_W(m));
        for (int j = tid; j < 4096; j += 256) {
            const float4 v = w4[j];
            const int b0 = (fabs((double)v.x) > thr) ? (v.x > 0.f ? 1 : -1) : 0;
            const int b1 = (fabs((double)v.y) > thr) ? (v.y > 0.f ? 1 : -1) : 0;
            const int b2 = (fabs((double)v.z) > thr) ? (v.z > 0.f ? 1 : -1) : 0;
            const int b3 = (fabs((double)v.w) > thr) ? (v.w > 0.f ? 1 : -1) : 0;
            tw[j] = (b0 & 0xff) | ((b1 & 0xff) << 8) | ((b2 & 0xff) << 16) | (b3 << 24);
        }
    } else {
        // 2048 blocks x 1024 float4s, fully unrolled independent loads
        const int idx = blockIdx.x - 4;
        const float4* x4 = (const float4*)x + (size_t)idx * 1024;
        float m0[4];
#pragma unroll
        for (int k = 0; k < 4; ++k) {
            const float4 v = x4[k * 256 + tid];
            m0[k] = fmaxf(fmaxf(fabsf(v.x), fabsf(v.y)), fmaxf(fabsf(v.z), fabsf(v.w)));
        }
        float mx = fmaxf(fmaxf(m0[0], m0[1]), fmaxf(m0[2], m0[3]));
#pragma unroll
        for (int off = 32; off; off >>= 1) mx = fmaxf(mx, __shfl_xor(mx, off));
        __shared__ float wred[4];
        if ((tid & 63) == 0) wred[tid >> 6] = mx;
        __syncthreads();
        if (tid == 0)
            ((float*)(ws + WS_PMAXX))[idx] =
                fmaxf(fmaxf(wred[0], wred[1]), fmaxf(wred[2], wred[3]));
    }
}

// ---- int8 MFMA QKV projection -------------------------------------------
// Prologue folds the 2048-partial max|x| reduction (L2-hit) — no separate
// 1-block reduce kernel serializing the device.
// blocks 0..1023: Q (all rows) -> QBUF head-major f16 (0.25 scale folded)
// blocks 1024..1151: K,V (window rows only) -> new_k/new_v region of d_out
__global__ __launch_bounds__(256) void qkv_proj_mfma(const float* __restrict__ x,
                                                     const float* __restrict__ qb,
                                                     const float* __restrict__ kb,
                                                     const float* __restrict__ vb,
                                                     char* __restrict__ ws,
                                                     float* __restrict__ out) {
    const int bx = blockIdx.x;
    const int tid = threadIdx.x;
    int proj, in_row0, b_blk, s0;   // s0: seq offset (Q) or window offset (K/V)
    if (bx < 1024) {
        proj = 0; in_row0 = bx * 64; b_blk = bx >> 5; s0 = (bx * 64) & 2047;
    } else {
        int widx = bx - 1024;
        proj = 1 + (widx >> 6);
        widx &= 63;
        b_blk = widx >> 1;
        s0 = (widx & 1) * 64;
        in_row0 = b_blk * 2048 + (SS - WINDOW) + s0;
    }
    const float* bias = (proj == 0) ? qb : (proj == 1) ? kb : vb;
    const signed char* tw = (const signed char*)(ws + WS_W(proj));
    float* dst = (proj == 1) ? (out + (size_t)ROWS * EE)
                             : (out + (size_t)ROWS * EE + NKV_N);   // K or V (unused for Q)
    _Float16* dstq = (_Float16*)(ws + WS_QBUF);

    const int lane = tid & 63;
    const int wv = tid >> 6;
    const int ml = lane & 15;
    const int quad = lane >> 4;

    // ---- prologue: reduce 2048 partial |x| maxes -> maxx ----
    __shared__ float xred[4];
    {
        const float4* pm = (const float4*)(ws + WS_PMAXX);
        float mo = 0.f;
#pragma unroll
        for (int k = 0; k < 2; ++k) {
            const float4 v = pm[k * 256 + tid];
            mo = fmaxf(mo, fmaxf(fmaxf(v.x, v.y), fmaxf(v.z, v.w)));
        }
#pragma unroll
        for (int off = 32; off; off >>= 1) mo = fmaxf(mo, __shfl_xor(mo, off));
        if ((tid & 63) == 0) xred[tid >> 6] = mo;
    }

    v4i bfrag[8][2];
#pragma unroll
    for (int c = 0; c < 8; ++c)
#pragma unroll
        for (int s = 0; s < 2; ++s)
            bfrag[c][s] = *(const v4i*)(tw + (c * 16 + ml) * 128 + s * 64 + quad * 16);

    __syncthreads();
    const float maxx = fmaxf(fmaxf(xred[0], xred[1]), fmaxf(xred[2], xred[3]));

    __shared__ __align__(16) signed char lds_a[64 * 144];
    const float iscale = maxx / 127.0f;
    const float inv = 1.0f / iscale;
    const float4* x4 = (const float4*)(x + (size_t)in_row0 * 128);
#pragma unroll
    for (int it = 0; it < 8; ++it) {
        const int i = tid + it * 256;
        const int row = i >> 5, c4 = i & 31;
        const float4 v = x4[i];
        // |x| <= maxx guarantees |x|*inv <= 127: no clamp needed
        const int i0 = (int)rintf(v.x * inv);
        const int i1 = (int)rintf(v.y * inv);
        const int i2 = (int)rintf(v.z * inv);
        const int i3 = (int)rintf(v.w * inv);
        const int packed = (i0 & 0xff) | ((i1 & 0xff) << 8) | ((i2 & 0xff) << 16) | (i3 << 24);
        *(int*)(lds_a + row * 144 + c4 * 4) = packed;
    }
    __syncthreads();

    const v4i afrag0 = *(const v4i*)(lds_a + (wv * 16 + ml) * 144 + quad * 16);
    const v4i afrag1 = *(const v4i*)(lds_a + (wv * 16 + ml) * 144 + 64 + quad * 16);

    const float wsc = ((const float*)(ws + WS_WS))[proj];
    const float scale = wsc * iscale;
    const int srow = s0 + wv * 16 + ml;

#pragma unroll
    for (int c = 0; c < 8; ++c) {
        v4i acc = {0, 0, 0, 0};
        // swapped operands: D = W · X^T ; lane(ml,quad) reg r = out[row=ml][col=c*16+quad*4+r]
        acc = __builtin_amdgcn_mfma_i32_16x16x64_i8(bfrag[c][0], afrag0, acc, 0, 0, 0);
        acc = __builtin_amdgcn_mfma_i32_16x16x64_i8(bfrag[c][1], afrag1, acc, 0, 0, 0);
        const float4 b4 = ((const float4*)bias)[c * 4 + quad];
        if (proj == 0) {
            f16x4 st;
            st[0] = (_Float16)(((float)acc[0] * scale + b4.x) * 0.25f);
            st[1] = (_Float16)(((float)acc[1] * scale + b4.y) * 0.25f);
            st[2] = (_Float16)(((float)acc[2] * scale + b4.z) * 0.25f);
            st[3] = (_Float16)(((float)acc[3] * scale + b4.w) * 0.25f);
            *(f16x4*)(dstq + ((size_t)(b_blk * NH + c) * SS + srow) * 16 + quad * 4) = st;
        } else {
            float4 st;
            st.x = (float)acc[0] * scale + b4.x;
            st.y = (float)acc[1] * scale + b4.y;
            st.z = (float)acc[2] * scale + b4.z;
            st.w = (float)acc[3] * scale + b4.w;
            *(float4*)(dst + ((size_t)(b_blk * NH + c) * WINDOW + srow) * 16 + quad * 4) = st;
        }
    }
}

// ---- attention: f16 MFMA, latency-optimized -----------------------------
// K staged f16 [j][d], V staged f16 TRANSPOSED [d][j] (one-time conversion);
// Q fragments prefetched; tree reductions; dual PV accumulators.
// Output written f16 to WS_ABUF (halves attn-out round-trip traffic).
__global__ __launch_bounds__(256, 4) void attention(const float* __restrict__ ck,
                                                    const float* __restrict__ cv,
                                                    char* __restrict__ ws,
                                                    float* __restrict__ out) {
    const int qs = blockIdx.x, h = blockIdx.y, b = blockIdx.z;
    __shared__ __align__(16) _Float16 ksh[144 * 16];   // [j][d]
    __shared__ __align__(16) _Float16 vshT[16 * 144];  // [d][j]
    __shared__ float red[256];
    const int tid = threadIdx.x;
    const float* nkbuf = out + (size_t)ROWS * EE;
    const float* nvbuf = nkbuf + NKV_N;
    _Float16* abuf = (_Float16*)(ws + WS_ABUF);

    // --- staging: window rows 4..131 vectorized, sinks 0..3, zero tail ---
    {
        const float4* kw4 = (const float4*)(nkbuf + (size_t)(b * NH + h) * WINDOW * 16);
        const float4* vw4 = (const float4*)(nvbuf + (size_t)(b * NH + h) * WINDOW * 16);
#pragma unroll
        for (int it = 0; it < 2; ++it) {
            const int i = tid + it * 256;          // 0..511 float4s
            const float4 kv = kw4[i];
            const float4 vv = vw4[i];
            const int j = 4 + (i >> 2);
            const int d0 = (i & 3) * 4;
            f16x4 kh;
            kh[0] = (_Float16)kv.x; kh[1] = (_Float16)kv.y;
            kh[2] = (_Float16)kv.z; kh[3] = (_Float16)kv.w;
            *(f16x4*)(ksh + j * 16 + d0) = kh;
            vshT[(d0 + 0) * 144 + j] = (_Float16)vv.x;
            vshT[(d0 + 1) * 144 + j] = (_Float16)vv.y;
            vshT[(d0 + 2) * 144 + j] = (_Float16)vv.z;
            vshT[(d0 + 3) * 144 + j] = (_Float16)vv.w;
        }
        if (tid < 64) {                            // sinks j=0..3
            const int j = tid >> 4, d = tid & 15;
            const float kv = ck[((size_t)(b * NH + h) * CACHE_LEN + j) * 16 + d];
            const float vv = cv[((size_t)(b * NH + h) * CACHE_LEN + j) * 16 + d];
            ksh[j * 16 + d] = (_Float16)kv;
            vshT[d * 144 + j] = (_Float16)vv;
        } else {                                   // zero tail j=132..143 (192 elems)
            const int e = tid - 64;
            const int j = 132 + (e >> 4), d = e & 15;
            ksh[j * 16 + d] = (_Float16)0.f;
            vshT[d * 144 + j] = (_Float16)0.f;
        }
    }
    __syncthreads();

    const int lane = tid & 63;
    const int wv = tid >> 6;
    const int ml = lane & 15;
    const int quad = lane >> 4;

    // K A-fragments: lane holds K[c*16+ml][quad*4 .. +3]
    // V^T A-fragments: lane holds V[c*16+quad*4+i][ml] = vshT[ml][c*16+quad*4+i]
    f16x4 kf[9], vf[9];
#pragma unroll
    for (int c = 0; c < 9; ++c) {
        kf[c] = *(const f16x4*)(ksh + (c * 16 + ml) * 16 + quad * 4);
        vf[c] = *(const f16x4*)(vshT + ml * 144 + c * 16 + quad * 4);
    }

    // prefetch all 4 Q fragments (batch the HBM latency)
    const _Float16* qbuf = (const _Float16*)(ws + WS_QBUF) + (size_t)(b * NH + h) * SS * 16;
    f16x4 qf[4];
#pragma unroll
    for (int t = 0; t < 4; ++t) {
        const int q0 = qs * 256 + (t * 4 + wv) * 16;
        qf[t] = *(const f16x4*)(qbuf + (size_t)(q0 + ml) * 16 + quad * 4);
    }

    float tm = 0.f;

#pragma unroll 1
    for (int t = 0; t < 4; ++t) {
        const int q0 = qs * 256 + (t * 4 + wv) * 16;

        // S^T[j][q]: lane (ml,quad) reg r holds score(j = c*16+quad*4+r, q = q0+ml)
        f32x4 s[9];
#pragma unroll
        for (int c = 0; c < 9; ++c) {
            f32x4 z = {0.f, 0.f, 0.f, 0.f};
            s[c] = __builtin_amdgcn_mfma_f32_16x16x16f16(kf[c], qf[t], z, 0, 0, 0);
        }
        // padded tail keys j=132..143 (chunk 8, quad>=1) are invalid
        if (quad >= 1) {
#pragma unroll
            for (int r = 0; r < 4; ++r) s[8][r] = -1e30f;
        }
        // causal mask: query q attends keys j <= min(q, 131); only q<=130 need it
        if (q0 <= 130) {
            const int jm = min(q0 + ml, KSEL - 1);
#pragma unroll
            for (int c = 0; c < 9; ++c)
#pragma unroll
                for (int r = 0; r < 4; ++r)
                    if (c * 16 + quad * 4 + r > jm) s[c][r] = -1e30f;
        }

        // ---- max: pairwise tree (depth ~6) + 2 shfl ----
        float mc[9];
#pragma unroll
        for (int c = 0; c < 9; ++c)
            mc[c] = fmaxf(fmaxf(s[c][0], s[c][1]), fmaxf(s[c][2], s[c][3]));
        const float t01 = fmaxf(mc[0], mc[1]), t23 = fmaxf(mc[2], mc[3]);
        const float t45 = fmaxf(mc[4], mc[5]), t67 = fmaxf(mc[6], mc[7]);
        float mx = fmaxf(fmaxf(fmaxf(t01, t23), fmaxf(t45, t67)), mc[8]);
        mx = fmaxf(mx, __shfl_xor(mx, 16));
        mx = fmaxf(mx, __shfl_xor(mx, 32));

        // ---- exp + sum: 4 parallel partial-sum chains ----
        f32x4 ls = {0.f, 0.f, 0.f, 0.f};
#pragma unroll
        for (int c = 0; c < 9; ++c) {
#pragma unroll
            for (int r = 0; r < 4; ++r) {
                const float p = __expf(s[c][r] - mx);
                s[c][r] = p;
                ls[r] += p;
            }
        }
        float lsum = (ls[0] + ls[1]) + (ls[2] + ls[3]);
        lsum += __shfl_xor(lsum, 16);
        lsum += __shfl_xor(lsum, 32);

        // ---- PV: O^T = V^T · P^T, dual accumulators (halved dep chain) ----
        f32x4 oA = {0.f, 0.f, 0.f, 0.f}, oB = {0.f, 0.f, 0.f, 0.f};
#pragma unroll
        for (int c = 0; c < 9; ++c) {
            union { fp16v2 h2[2]; f16x4 h4; } u;
            u.h2[0] = __builtin_amdgcn_cvt_pkrtz(s[c][0], s[c][1]);
            u.h2[1] = __builtin_amdgcn_cvt_pkrtz(s[c][2], s[c][3]);
            if (c & 1) oB = __builtin_amdgcn_mfma_f32_16x16x16f16(vf[c], u.h4, oB, 0, 0, 0);
            else       oA = __builtin_amdgcn_mfma_f32_16x16x16f16(vf[c], u.h4, oA, 0, 0, 0);
        }

        const float inv = 1.0f / lsum;
        float4 ov;
        ov.x = (oA[0] + oB[0]) * inv;
        ov.y = (oA[1] + oB[1]) * inv;
        ov.z = (oA[2] + oB[2]) * inv;
        ov.w = (oA[3] + oB[3]) * inv;
        tm = fmaxf(tm, fmaxf(fmaxf(fabsf(ov.x), fabsf(ov.y)), fmaxf(fabsf(ov.z), fabsf(ov.w))));
        // lane writes f16 O[q0+ml][quad*4 .. +3] of head h into ABUF
        f16x4 oh;
        oh[0] = (_Float16)ov.x; oh[1] = (_Float16)ov.y;
        oh[2] = (_Float16)ov.z; oh[3] = (_Float16)ov.w;
        *(f16x4*)(abuf + ((size_t)(b * SS + q0 + ml)) * 128 + h * 16 + quad * 4) = oh;
    }

    red[tid] = tm;
    __syncthreads();
    for (int st = 128; st > 0; st >>= 1) {
        if (tid < st) red[tid] = fmaxf(red[tid], red[tid + st]);
        __syncthreads();
    }
    if (tid == 0) {
        const int id = qs + 8 * h + 64 * b;      // 0..2047
        ((float*)(ws + WS_PMAXO))[id] = red[0];
    }
}

// ---- O projection, int8 MFMA: reads f16 ABUF, writes final f32 d_out ----
// Starts by reducing the 2048 per-block attention maxes (L2-hit reads).
__global__ __launch_bounds__(256) void o_proj_mfma(const float* __restrict__ ob,
                                                   char* __restrict__ ws,
                                                   float* __restrict__ out) {
    const int bx = blockIdx.x;
    const int tid = threadIdx.x;
    const int in_row0 = bx * 64;
    const signed char* tw = (const signed char*)(ws + WS_W(3));

    const int lane = tid & 63;
    const int wv = tid >> 6;
    const int ml = lane & 15;
    const int quad = lane >> 4;

    // ---- reduce 2048 partial maxes -> maxo ----
    __shared__ float ored[4];
    {
        const float4* pm = (const float4*)(ws + WS_PMAXO);
        float mo = 0.f;
#pragma unroll
        for (int k = 0; k < 2; ++k) {
            const float4 v = pm[k * 256 + tid];
            mo = fmaxf(mo, fmaxf(fmaxf(v.x, v.y), fmaxf(v.z, v.w)));
        }
#pragma unroll
        for (int off = 32; off; off >>= 1) mo = fmaxf(mo, __shfl_xor(mo, off));
        if ((tid & 63) == 0) ored[tid >> 6] = mo;
    }

    v4i bfrag[8][2];
#pragma unroll
    for (int c = 0; c < 8; ++c)
#pragma unroll
        for (int s = 0; s < 2; ++s)
            bfrag[c][s] = *(const v4i*)(tw + (c * 16 + ml) * 128 + s * 64 + quad * 16);

    __syncthreads();
    const float maxo = fmaxf(fmaxf(ored[0], ored[1]), fmaxf(ored[2], ored[3]));

    __shared__ __align__(16) signed char lds_a[64 * 144];
    const float iscale = maxo / 127.0f;
    const float inv = 1.0f / iscale;
    const _Float16* abuf = (const _Float16*)(ws + WS_ABUF);
#pragma unroll
    for (int it = 0; it < 4; ++it) {
        const int i = tid + it * 256;              // 0..1023 f16x8 chunks
        const int row = i >> 4, c8 = i & 15;
        const f16x8 v = *(const f16x8*)(abuf + (size_t)(in_row0 + row) * 128 + c8 * 8);
        // |attn_out| <= maxo (f16 round-up <= 0.05% -> still rints to <=127)
        const int i0 = (int)rintf((float)v[0] * inv);
        const int i1 = (int)rintf((float)v[1] * inv);
        const int i2 = (int)rintf((float)v[2] * inv);
        const int i3 = (int)rintf((float)v[3] * inv);
        const int i4 = (int)rintf((float)v[4] * inv);
        const int i5 = (int)rintf((float)v[5] * inv);
        const int i6 = (int)rintf((float)v[6] * inv);
        const int i7 = (int)rintf((float)v[7] * inv);
        const int p0 = (i0 & 0xff) | ((i1 & 0xff) << 8) | ((i2 & 0xff) << 16) | (i3 << 24);
        const int p1 = (i4 & 0xff) | ((i5 & 0xff) << 8) | ((i6 & 0xff) << 16) | (i7 << 24);
        *(int*)(lds_a + row * 144 + c8 * 8) = p0;
        *(int*)(lds_a + row * 144 + c8 * 8 + 4) = p1;
    }
    __syncthreads();

    const v4i afrag0 = *(const v4i*)(lds_a + (wv * 16 + ml) * 144 + quad * 16);
    const v4i afrag1 = *(const v4i*)(lds_a + (wv * 16 + ml) * 144 + 64 + quad * 16);

    const float wsc = ((const float*)(ws + WS_WS))[3];
    const float scale = wsc * iscale;
    const int orow = in_row0 + wv * 16 + ml;

#pragma unroll
    for (int c = 0; c < 8; ++c) {
        v4i acc = {0, 0, 0, 0};
        // swapped operands: lane(ml,quad) reg r = out[row=ml][col=c*16+quad*4+r]
        acc = __builtin_amdgcn_mfma_i32_16x16x64_i8(bfrag[c][0], afrag0, acc, 0, 0, 0);
        acc = __builtin_amdgcn_mfma_i32_16x16x64_i8(bfrag[c][1], afrag1, acc, 0, 0, 0);
        const float4 b4 = ((const float4*)ob)[c * 4 + quad];
        float4 st;
        st.x = (float)acc[0] * scale + b4.x;
        st.y = (float)acc[1] * scale + b4.y;
        st.z = (float)acc[2] * scale + b4.z;
        st.w = (float)acc[3] * scale + b4.w;
        *(float4*)(out + (size_t)orow * 128 + c * 16 + quad * 4) = st;
    }
}

extern "C" void kernel_launch(void* const* d_in, const int* in_sizes, int n_in,
                              void* d_out, int out_size, void* d_ws, size_t ws_size,
                              hipStream_t stream) {
    const float* x  = (const float*)d_in[0];
    const float* ck = (const float*)d_in[1];
    const float* cv = (const float*)d_in[2];
    const float* qw = (const float*)d_in[3];
    const float* qb = (const float*)d_in[4];
    const float* kw = (const float*)d_in[5];
    const float* kb = (const float*)d_in[6];
    const float* vw = (const float*)d_in[7];
    const float* vb = (const float*)d_in[8];
    const float* ow = (const float*)d_in[9];
    const float* ob = (const float*)d_in[10];
    char* ws = (char*)d_ws;
    float* out = (float*)d_out;

    prep_and_max<<<4 + 2048, 256, 0, stream>>>(qw, kw, vw, ow, x, ws);
    qkv_proj_mfma<<<1024 + 128, 256, 0, stream>>>(x, qb, kb, vb, ws, out);
    attention<<<dim3(8, NH, BB), 256, 0, stream>>>(ck, cv, ws, out);
    o_proj_mfma<<<1024, 256, 0, stream>>>(ob, ws, out);
}